// Round 3
// baseline (135.782 us; speedup 1.0000x reference)
//
#include <hip/hip_runtime.h>
#include <hip/hip_cooperative_groups.h>
#include <math.h>

namespace cg = cooperative_groups;

constexpr int BB   = 2;
constexpr int NN   = 512;
constexpr int FIN  = 256;
constexpr int FOUT = 128;
constexpr int NBLK = 512;   // 2 blocks/CU on 256 CUs
constexpr int NTHR = 256;   // 4 waves/block -> 2 waves/SIMD

// One fused cooperative kernel:
//  A: Wh = x@W, u_i = sum_o a_o*Wh[i,o]          (2 rows/block)
//  B: e[i,j] = 0.6(u_i+u_j) + sum_o 0.4a_o*|Wh_io+Wh_jo|, + sumsq partials
//     (1 32x32 tile/block; lrelu(s)=0.6s+0.4|s| rank-1 split)
//  C: global-norm -> mask -> row softmax -> att@Wh -> elu
//     (4 rows x 64-o-half per block)
__global__ __launch_bounds__(NTHR, 2) void gat_fused(
        const float* __restrict__ x, const int* __restrict__ adj,
        const float* __restrict__ W, const float* __restrict__ a_fc,
        float* __restrict__ out, float* __restrict__ Wh,
        float* __restrict__ u, float* __restrict__ e_buf,
        float* __restrict__ partials) {
    cg::grid_group grid = cg::this_grid();
    __shared__ float lds[8704];   // 34.8 KB: phase-B layout is the max

    const int t  = threadIdx.x;
    const int bx = blockIdx.x;

    // ---------------- Phase A: Wh + u (2 rows per block) ----------------
    {
        float* xs  = lds;          // [2][256]
        float* red = lds + 512;    // [4]
        const int g0 = bx * 2;     // global row (b*N + n)

        const float4* xg = (const float4*)(x + (size_t)g0 * FIN);
        if (t < 128) ((float4*)xs)[t] = xg[t];
        __syncthreads();

        const int rl = t >> 7;     // 0..1
        const int o  = t & 127;
        const float* xr = xs + rl * FIN;
        float acc = 0.f;
#pragma unroll 8
        for (int f = 0; f < FIN; ++f)
            acc = fmaf(xr[f], W[f * FOUT + o], acc);
        Wh[(size_t)(g0 + rl) * FOUT + o] = acc;

        float pa = acc * a_fc[o];
#pragma unroll
        for (int off = 32; off; off >>= 1) pa += __shfl_down(pa, off);
        if ((t & 63) == 0) red[t >> 6] = pa;
        __syncthreads();
        if (t == 0) { u[g0] = red[0] + red[1]; u[g0 + 1] = red[2] + red[3]; }
    }
    grid.sync();

    // ---------------- Phase B: e tile 32x32 per block ----------------
    {
        float* whi = lds;            // [32][132]
        float* whj = lds + 4224;     // [32][132]
        float* a2  = lds + 8448;     // [128] = 0.4*a
        float* usi = lds + 8576;     // [32]
        float* usj = lds + 8608;     // [32]
        float* red = lds + 8640;     // [4]

        const int b   = bx >> 8;
        const int ti  = (bx >> 4) & 15;
        const int tj  = bx & 15;
        const int bi0 = ti * 32, bj0 = tj * 32;
        const int rowbase = b * NN;
        const float* whb = Wh + (size_t)rowbase * FOUT;

        if (t < 128) a2[t] = 0.4f * a_fc[t];
        if (t < 32)       usi[t]      = u[rowbase + bi0 + t];
        else if (t < 64)  usj[t - 32] = u[rowbase + bj0 + (t - 32)];

#pragma unroll
        for (int it = 0; it < 4; ++it) {
            const int idx = it * 256 + t;   // float4 index 0..1023
            const int row = idx >> 5, c4 = idx & 31;
            *(float4*)&whi[row * 132 + c4 * 4] =
                *(const float4*)(whb + (size_t)(bi0 + row) * FOUT + c4 * 4);
            *(float4*)&whj[row * 132 + c4 * 4] =
                *(const float4*)(whb + (size_t)(bj0 + row) * FOUT + c4 * 4);
        }
        __syncthreads();

        const int gi = t >> 4;   // 0..15
        const int gj = t & 15;   // 0..15
        float acc[2][2] = {{0.f, 0.f}, {0.f, 0.f}};

        for (int c = 0; c < 32; ++c) {
            const float4 av  = *(const float4*)&a2[c * 4];
            const float4 wi0 = *(const float4*)&whi[gi * 132 + c * 4];
            const float4 wi1 = *(const float4*)&whi[(gi + 16) * 132 + c * 4];
            const float4 wj0 = *(const float4*)&whj[gj * 132 + c * 4];
            const float4 wj1 = *(const float4*)&whj[(gj + 16) * 132 + c * 4];
#define GAT_ACC(ri, rj, WI, WJ)                                        \
            {                                                          \
                float s;                                               \
                s = WI.x + WJ.x; acc[ri][rj] = fmaf(av.x, fabsf(s), acc[ri][rj]); \
                s = WI.y + WJ.y; acc[ri][rj] = fmaf(av.y, fabsf(s), acc[ri][rj]); \
                s = WI.z + WJ.z; acc[ri][rj] = fmaf(av.z, fabsf(s), acc[ri][rj]); \
                s = WI.w + WJ.w; acc[ri][rj] = fmaf(av.w, fabsf(s), acc[ri][rj]); \
            }
            GAT_ACC(0, 0, wi0, wj0)
            GAT_ACC(0, 1, wi0, wj1)
            GAT_ACC(1, 0, wi1, wj0)
            GAT_ACC(1, 1, wi1, wj1)
#undef GAT_ACC
        }

        float ss = 0.f;
#pragma unroll
        for (int ri = 0; ri < 2; ++ri) {
#pragma unroll
            for (int rj = 0; rj < 2; ++rj) {
                const int ii = gi + 16 * ri, jj = gj + 16 * rj;
                const float ev = fmaf(0.6f, usi[ii] + usj[jj], acc[ri][rj]);
                ss = fmaf(ev, ev, ss);
                e_buf[((size_t)(rowbase + bi0 + ii)) * NN + (bj0 + jj)] = ev;
            }
        }
#pragma unroll
        for (int off = 32; off; off >>= 1) ss += __shfl_down(ss, off);
        if ((t & 63) == 0) red[t >> 6] = ss;
        __syncthreads();
        if (t == 0) partials[bx] = red[0] + red[1] + red[2] + red[3];
    }
    grid.sync();

    // ---------------- Phase C: norm/softmax/PV/elu ----------------
    {
        float* p     = lds;           // [4][512]
        float* hb    = lds + 2048;    // [3][4][64]
        float* smax  = lds + 2816;    // [4][4]
        float* ssum  = lds + 2832;    // [4][4]
        float* snorm = lds + 2848;    // [4]

        const int g0    = (bx & 255) * 4;
        const int ohalf = bx >> 8;
        const int w     = t >> 6;

        // global Frobenius norm from 512 partials
        float v = partials[t] + partials[t + 256];
#pragma unroll
        for (int off = 32; off; off >>= 1) v += __shfl_down(v, off);
        if ((t & 63) == 0) snorm[w] = v;
        __syncthreads();
        const float inv_norm =
            1.0f / sqrtf(snorm[0] + snorm[1] + snorm[2] + snorm[3]);

        float rs[4];
#pragma unroll
        for (int r = 0; r < 4; ++r) {
            const int g = g0 + r;
            const float* erow = e_buf + (size_t)g * NN;
            const int*   arow = adj   + (size_t)g * NN;

            const float e0 = arow[t]       ? erow[t]       * inv_norm : -INFINITY;
            const float e1 = arow[t + 256] ? erow[t + 256] * inv_norm : -INFINITY;

            float mx = fmaxf(e0, e1);
#pragma unroll
            for (int off = 32; off; off >>= 1) mx = fmaxf(mx, __shfl_down(mx, off));
            if ((t & 63) == 0) smax[r * 4 + w] = mx;
            __syncthreads();
            mx = fmaxf(fmaxf(smax[r * 4 + 0], smax[r * 4 + 1]),
                       fmaxf(smax[r * 4 + 2], smax[r * 4 + 3]));

            const float p0 = expf(e0 - mx);
            const float p1 = expf(e1 - mx);
            p[r * NN + t]       = p0;
            p[r * NN + t + 256] = p1;

            float sm = p0 + p1;
#pragma unroll
            for (int off = 32; off; off >>= 1) sm += __shfl_down(sm, off);
            __syncthreads();
            if ((t & 63) == 0) ssum[r * 4 + w] = sm;
            __syncthreads();
            rs[r] = 1.0f / (ssum[r * 4 + 0] + ssum[r * 4 + 1] +
                            ssum[r * 4 + 2] + ssum[r * 4 + 3]);
        }
        __syncthreads();

        // PV: 4 rows x 64 o's per block; j split across the 4 waves
        const int b = g0 >> 9;
        const float* whb = Wh + (size_t)(b * NN) * FOUT;
        const int oo = t & 63;
        const int o  = ohalf * 64 + oo;
        const int h  = t >> 6;            // 0..3
        float a4[4] = {0.f, 0.f, 0.f, 0.f};
        const int j0 = h * 128;
#pragma unroll 4
        for (int j = j0; j < j0 + 128; ++j) {
            const float wv = whb[(size_t)j * FOUT + o];
            a4[0] = fmaf(p[0 * NN + j], wv, a4[0]);
            a4[1] = fmaf(p[1 * NN + j], wv, a4[1]);
            a4[2] = fmaf(p[2 * NN + j], wv, a4[2]);
            a4[3] = fmaf(p[3 * NN + j], wv, a4[3]);
        }

        if (h) {
#pragma unroll
            for (int r = 0; r < 4; ++r)
                hb[(h - 1) * 256 + r * 64 + oo] = a4[r];
        }
        __syncthreads();
        if (h == 0) {
#pragma unroll
            for (int r = 0; r < 4; ++r) {
                const float hv = (a4[r] + hb[r * 64 + oo] +
                                  hb[256 + r * 64 + oo] +
                                  hb[512 + r * 64 + oo]) * rs[r];
                out[(size_t)(g0 + r) * FOUT + o] =
                    (hv > 0.f) ? hv : expm1f(hv);
            }
        }
    }
}

// ---------------------------------------------------------------------------
extern "C" void kernel_launch(void* const* d_in, const int* in_sizes, int n_in,
                              void* d_out, int out_size, void* d_ws, size_t ws_size,
                              hipStream_t stream) {
    const float* x    = (const float*)d_in[0];
    const int*   adj  = (const int*)d_in[1];
    const float* W    = (const float*)d_in[2];
    const float* a_fc = (const float*)d_in[3];
    float* out = (float*)d_out;

    float* ws       = (float*)d_ws;
    float* Wh       = ws;                            // 131072 floats
    float* u        = ws + 131072;                   // 1024
    float* partials = ws + 131072 + 1024;            // 512
    float* e_buf    = ws + 131072 + 1024 + 512;      // 524288

    void* args[] = {(void*)&x, (void*)&adj, (void*)&W, (void*)&a_fc,
                    (void*)&out, (void*)&Wh, (void*)&u, (void*)&e_buf,
                    (void*)&partials};
    hipLaunchCooperativeKernel((const void*)gat_fused, dim3(NBLK), dim3(NTHR),
                               args, 0, stream);
}

// Round 4
// 28.631 us; speedup vs baseline: 4.7424x; 4.7424x over previous
//
#include <hip/hip_runtime.h>
#include <math.h>

constexpr int BB   = 2;
constexpr int NN   = 512;
constexpr int FIN  = 256;
constexpr int FOUT = 128;

// ---------------------------------------------------------------------------
// Kernel A: Wh = x@W and u_i = sum_o a_o*Wh[i,o]
// 256 blocks x 512 thr. Block = 4 rows. Thread: (rl=t>>7, fs=(t>>5)&3, og=t&31)
// computes float4 partial over 64 f's; combine across fs via LDS.
// ---------------------------------------------------------------------------
__global__ __launch_bounds__(512) void wh_u_kernel(const float* __restrict__ x,
                                                   const float* __restrict__ W,
                                                   const float* __restrict__ a_fc,
                                                   float* __restrict__ Wh,
                                                   float* __restrict__ u) {
    __shared__ float  xs[4][FIN];
    __shared__ float4 part[4][4][32];

    const int t  = threadIdx.x;
    const int g0 = blockIdx.x * 4;

    if (t < 256)
        ((float4*)xs)[t] = ((const float4*)(x + (size_t)g0 * FIN))[t];
    __syncthreads();

    const int rl = t >> 7;
    const int fs = (t >> 5) & 3;
    const int og = t & 31;
    const float* xr = &xs[rl][fs * 64];
    const float4* W4 = (const float4*)W;

    float4 acc = {0.f, 0.f, 0.f, 0.f};
#pragma unroll 8
    for (int f = 0; f < 64; ++f) {
        const float  xv = xr[f];
        const float4 wv = W4[(size_t)(fs * 64 + f) * 32 + og];
        acc.x = fmaf(xv, wv.x, acc.x);
        acc.y = fmaf(xv, wv.y, acc.y);
        acc.z = fmaf(xv, wv.z, acc.z);
        acc.w = fmaf(xv, wv.w, acc.w);
    }
    part[rl][fs][og] = acc;
    __syncthreads();

    if (fs == 0) {   // lanes 0..31 of waves 0,2,4,6
        const float4 s0 = part[rl][0][og];
        const float4 s1 = part[rl][1][og];
        const float4 s2 = part[rl][2][og];
        const float4 s3 = part[rl][3][og];
        float4 w4;
        w4.x = (s0.x + s1.x) + (s2.x + s3.x);
        w4.y = (s0.y + s1.y) + (s2.y + s3.y);
        w4.z = (s0.z + s1.z) + (s2.z + s3.z);
        w4.w = (s0.w + s1.w) + (s2.w + s3.w);
        ((float4*)(Wh + (size_t)(g0 + rl) * FOUT))[og] = w4;

        const float4 a4 = ((const float4*)a_fc)[og];
        float pa = w4.x * a4.x + w4.y * a4.y + w4.z * a4.z + w4.w * a4.w;
#pragma unroll
        for (int off = 16; off; off >>= 1) pa += __shfl_down(pa, off, 32);
        if (og == 0) u[g0 + rl] = pa;
    }
}

// ---------------------------------------------------------------------------
// Kernel B: e[i,j] = 0.6(u_i+u_j) + sum_o (0.4 a_o)|Wh_io+Wh_jo|  + sumsq part
// grid (32 j-tiles, 8 i-tiles, 2 b), 256 thr. Tile 64i x 16j.
// Wave w owns o-chunk [32w,32w+32): lane=i keeps its i-slice in REGISTERS,
// j-rows are LDS broadcast reads (conflict-free). Per-wave partials combined
// through padded parts[16][4][65].
// ---------------------------------------------------------------------------
__global__ __launch_bounds__(256) void e_kernel(const float* __restrict__ Wh,
                                                const float* __restrict__ u,
                                                const float* __restrict__ a_fc,
                                                float* __restrict__ e_buf,
                                                float* __restrict__ partials) {
    __shared__ float whi[64][132];
    __shared__ float whj[16][132];
    __shared__ float a2[FOUT];
    __shared__ float usi[64];
    __shared__ float usj[16];
    __shared__ float parts[16][4][65];
    __shared__ float red[4];

    const int t   = threadIdx.x;
    const int bj0 = blockIdx.x * 16;
    const int bi0 = blockIdx.y * 64;
    const int b   = blockIdx.z;
    const float* whb = Wh + (size_t)(b * NN) * FOUT;

#pragma unroll
    for (int it = 0; it < 8; ++it) {
        const int idx = it * 256 + t;
        const int row = idx >> 5, c4 = idx & 31;
        *(float4*)&whi[row][c4 * 4] =
            *(const float4*)(whb + (size_t)(bi0 + row) * FOUT + c4 * 4);
    }
#pragma unroll
    for (int it = 0; it < 2; ++it) {
        const int idx = it * 256 + t;
        const int row = idx >> 5, c4 = idx & 31;
        *(float4*)&whj[row][c4 * 4] =
            *(const float4*)(whb + (size_t)(bj0 + row) * FOUT + c4 * 4);
    }
    if (t < 64)                usi[t]       = u[b * NN + bi0 + t];
    else if (t < 80)           usj[t - 64]  = u[b * NN + bj0 + (t - 64)];
    else if (t >= 128)         a2[t - 128]  = 0.4f * a_fc[t - 128];
    __syncthreads();

    const int w    = t >> 6;
    const int lane = t & 63;
    const int ob   = w * 32;

    float4 iv[8], av[8];
#pragma unroll
    for (int k = 0; k < 8; ++k) {
        iv[k] = *(const float4*)&whi[lane][ob + 4 * k];
        av[k] = *(const float4*)&a2[ob + 4 * k];
    }

#pragma unroll 2
    for (int j = 0; j < 16; ++j) {
        float4 acc = {0.f, 0.f, 0.f, 0.f};
#pragma unroll
        for (int k = 0; k < 8; ++k) {
            const float4 jv = *(const float4*)&whj[j][ob + 4 * k];
            float s;
            s = iv[k].x + jv.x; acc.x = fmaf(av[k].x, fabsf(s), acc.x);
            s = iv[k].y + jv.y; acc.y = fmaf(av[k].y, fabsf(s), acc.y);
            s = iv[k].z + jv.z; acc.z = fmaf(av[k].z, fabsf(s), acc.z);
            s = iv[k].w + jv.w; acc.w = fmaf(av[k].w, fabsf(s), acc.w);
        }
        parts[j][w][lane] = (acc.x + acc.y) + (acc.z + acc.w);
    }
    __syncthreads();

    // combine: thread -> i = t>>2 (0..63), j-quad = t&3
    const int i  = t >> 2;
    const int jq = t & 3;
    const float ui = usi[i];
    float ev[4];
    float ss = 0.f;
#pragma unroll
    for (int jj = 0; jj < 4; ++jj) {
        const int j = jq * 4 + jj;
        const float s4 = (parts[j][0][i] + parts[j][1][i]) +
                         (parts[j][2][i] + parts[j][3][i]);
        const float v = fmaf(0.6f, ui + usj[j], s4);
        ss = fmaf(v, v, ss);
        ev[jj] = v;
    }
    float4 e4 = {ev[0], ev[1], ev[2], ev[3]};
    *(float4*)&e_buf[(size_t)(b * NN + bi0 + i) * NN + bj0 + jq * 4] = e4;

#pragma unroll
    for (int off = 32; off; off >>= 1) ss += __shfl_down(ss, off);
    if ((t & 63) == 0) red[t >> 6] = ss;
    __syncthreads();
    if (t == 0)
        partials[(blockIdx.z * 8 + blockIdx.y) * 32 + blockIdx.x] =
            (red[0] + red[1]) + (red[2] + red[3]);
}

// ---------------------------------------------------------------------------
// Kernel C: norm -> mask -> softmax -> att@Wh -> elu
// 512 blocks x 256 thr: (4 rows) x (64-o half). Wave w owns row w: softmax is
// pure shfl_xor (no barriers). PV: j-quarter per wave, combine via LDS.
// ---------------------------------------------------------------------------
__global__ __launch_bounds__(256) void softmax_pv_kernel(
        const float* __restrict__ e_buf, const int* __restrict__ adj,
        const float* __restrict__ Wh, const float* __restrict__ partials,
        float* __restrict__ out) {
    __shared__ float p[4][NN];
    __shared__ float hb[3][4][64];
    __shared__ float red[4];
    __shared__ float rsv[4];

    const int t    = threadIdx.x;
    const int w    = t >> 6;
    const int lane = t & 63;

    // global Frobenius norm from 512 partials
    float v = partials[t] + partials[t + 256];
#pragma unroll
    for (int off = 32; off; off >>= 1) v += __shfl_down(v, off);
    if (lane == 0) red[w] = v;
    __syncthreads();
    const float inv_norm = 1.0f / sqrtf((red[0] + red[1]) + (red[2] + red[3]));

    const int g0  = (blockIdx.x & 255) * 4;
    const int row = g0 + w;

    const float4* er4 = (const float4*)(e_buf + (size_t)row * NN);
    const int4*   ad4 = (const int4*)(adj + (size_t)row * NN);
    const float4 ea = er4[lane],     eb = er4[lane + 64];
    const int4   aa = ad4[lane],     ab = ad4[lane + 64];

    float va[8];
    va[0] = aa.x ? ea.x * inv_norm : -INFINITY;
    va[1] = aa.y ? ea.y * inv_norm : -INFINITY;
    va[2] = aa.z ? ea.z * inv_norm : -INFINITY;
    va[3] = aa.w ? ea.w * inv_norm : -INFINITY;
    va[4] = ab.x ? eb.x * inv_norm : -INFINITY;
    va[5] = ab.y ? eb.y * inv_norm : -INFINITY;
    va[6] = ab.z ? eb.z * inv_norm : -INFINITY;
    va[7] = ab.w ? eb.w * inv_norm : -INFINITY;

    float mx = va[0];
#pragma unroll
    for (int c = 1; c < 8; ++c) mx = fmaxf(mx, va[c]);
#pragma unroll
    for (int off = 32; off; off >>= 1) mx = fmaxf(mx, __shfl_xor(mx, off));

    float pv[8], sum = 0.f;
#pragma unroll
    for (int c = 0; c < 8; ++c) { pv[c] = expf(va[c] - mx); sum += pv[c]; }
    float4 pa = {pv[0], pv[1], pv[2], pv[3]};
    float4 pb = {pv[4], pv[5], pv[6], pv[7]};
    ((float4*)&p[w][0])[lane]      = pa;
    ((float4*)&p[w][0])[lane + 64] = pb;

#pragma unroll
    for (int off = 32; off; off >>= 1) sum += __shfl_xor(sum, off);
    if (lane == 0) rsv[w] = 1.0f / sum;
    __syncthreads();

    // PV: o-half per block, j-quarter per wave
    const int oo = lane;
    const int o  = (blockIdx.x >> 8) * 64 + oo;
    const int b  = g0 >> 9;
    const float* whb = Wh + (size_t)(b * NN) * FOUT;
    const int j0 = w * 128;

    float acc[4] = {0.f, 0.f, 0.f, 0.f};
    for (int j = j0; j < j0 + 128; j += 4) {
        const float4 p0 = *(const float4*)&p[0][j];
        const float4 p1 = *(const float4*)&p[1][j];
        const float4 p2 = *(const float4*)&p[2][j];
        const float4 p3 = *(const float4*)&p[3][j];
        const float q0[4] = {p0.x, p0.y, p0.z, p0.w};
        const float q1[4] = {p1.x, p1.y, p1.z, p1.w};
        const float q2[4] = {p2.x, p2.y, p2.z, p2.w};
        const float q3[4] = {p3.x, p3.y, p3.z, p3.w};
#pragma unroll
        for (int q = 0; q < 4; ++q) {
            const float wv = whb[(size_t)(j + q) * FOUT + o];
            acc[0] = fmaf(q0[q], wv, acc[0]);
            acc[1] = fmaf(q1[q], wv, acc[1]);
            acc[2] = fmaf(q2[q], wv, acc[2]);
            acc[3] = fmaf(q3[q], wv, acc[3]);
        }
    }

    if (w) {
        hb[w - 1][0][oo] = acc[0];
        hb[w - 1][1][oo] = acc[1];
        hb[w - 1][2][oo] = acc[2];
        hb[w - 1][3][oo] = acc[3];
    }
    __syncthreads();
    if (w == 0) {
#pragma unroll
        for (int r = 0; r < 4; ++r) {
            const float hv = (acc[r] + hb[0][r][oo] + hb[1][r][oo] + hb[2][r][oo]) * rsv[r];
            out[(size_t)(g0 + r) * FOUT + o] = (hv > 0.f) ? hv : expm1f(hv);
        }
    }
}

// ---------------------------------------------------------------------------
extern "C" void kernel_launch(void* const* d_in, const int* in_sizes, int n_in,
                              void* d_out, int out_size, void* d_ws, size_t ws_size,
                              hipStream_t stream) {
    const float* x    = (const float*)d_in[0];
    const int*   adj  = (const int*)d_in[1];
    const float* W    = (const float*)d_in[2];
    const float* a_fc = (const float*)d_in[3];
    float* out = (float*)d_out;

    float* ws       = (float*)d_ws;
    float* Wh       = ws;                        // 131072 floats
    float* u        = ws + 131072;               // 1024
    float* partials = ws + 131072 + 1024;        // 512
    float* e_buf    = ws + 131072 + 1024 + 512;  // 524288

    wh_u_kernel<<<dim3(BB * NN / 4), dim3(512), 0, stream>>>(x, W, a_fc, Wh, u);
    e_kernel<<<dim3(NN / 16, NN / 64, BB), dim3(256), 0, stream>>>(Wh, u, a_fc, e_buf, partials);
    softmax_pv_kernel<<<dim3(BB * NN / 4 * 2), dim3(256), 0, stream>>>(e_buf, adj, Wh, partials, out);
}